// Round 10
// baseline (98.047 us; speedup 1.0000x reference)
//
#include <hip/hip_runtime.h>
#include <hip/hip_bf16.h>
#include <stdint.h>

#define N_TOKENS    16384
#define MODEL_DIM   2048
#define NUM_EXPERTS 16
#define CAPACITY    2048
#define NBLK        256    // 64-token chunks for routing/ballot
#define GBLK        2048   // gemv blocks (8 tokens each)
// d_out is FLOAT32. Element layout: [0]=l_aux, [1..32769)=weights[N][2],
// [32769..65537)=indices[E*CAP], [65537..98305)=expert_ids[E*CAP]
#define W_OFF       1
#define IDX_OFF     (1 + 2 * N_TOKENS)                  // 32769
#define EID_OFF     (IDX_OFF + NUM_EXPERTS * CAPACITY)  // 65537

// Scratch plan (all inside d_out, race-free by same-stream ordering):
//  - me partials (float [2048][16] = 128 KB) live in the INDICES region:
//    written by k_logits, read by k_finish, then overwritten by k_scatter/
//    k_fill_idx which produce the real indices content.
//  - e01/cnt/start/ce2 (40 KB) live in the EXPERT_IDS region; clobbered only
//    by the FINAL kernel k_eid.
#define SCR_BYTE  (4 * EID_OFF)
#define SC_E01    0        // uint8  [16384]: e1 | (e2<<4)
#define SC_CNT    16384    // uint16 [16][256] routed counts per 64-chunk
#define SC_START  24576    // uint16 [16][256] exclusive prefix
#define SC_CE2    32768    // uint16 [16][256] argmax counts per 64-chunk

// DPP butterfly add (intra-16-lane): xor1=0xB1, xor2=0x4E,
// xor7=ROW_HALF_MIRROR=0x141, xor15=ROW_MIRROR=0x140.
#define DPP_ADD(v, ctrl)                                                      \
  (v) += __int_as_float(__builtin_amdgcn_update_dpp(                          \
      0, __float_as_int(v), (ctrl), 0xF, 0xF, true))

__device__ __forceinline__ float dot4(float4 a, float4 b) {
  return a.x * b.x + a.y * b.y + a.z * b.z + a.w * b.w;
}

// ============ K1: GEMV logits + softmax + top2 + weights + me ============
// 2048 blocks x 256 thr (4 waves; ~45-55 VGPR -> 8 blocks/CU, 32 waves/CU =
// FULL occupancy). Block b: tokens [b*8, b*8+8). Wave wv: tokens wv*2, wv*2+1.
// Lane (kg=l&15, eg=l>>4): expert group eg owns experts eg*4..+3; kg lanes
// cover a 64-float k-chunk (j=0..31). acc = 2 float4 only. x coalesced
// (256B/instr, broadcast x4 groups via coalescer), read once. wg from L1.
__global__ __launch_bounds__(256) void k_logits(
    const float* __restrict__ x, const float* __restrict__ wg,
    float* __restrict__ out, float* __restrict__ me, uint8_t* __restrict__ scr)
{
  __shared__ float red[8][20];         // 8 tokens x 16 experts (pad 20)
  const int tid = threadIdx.x;
  const int b = blockIdx.x;
  const int l = tid & 63;
  const int wv = tid >> 6;
  const int kg = l & 15;
  const int eg = l >> 4;
  const int t0 = b * 8 + wv * 2;
  const float* xp = x + (size_t)t0 * MODEL_DIM + kg * 4;
  const float* wp = wg + (size_t)(eg * 4) * MODEL_DIM + kg * 4;

  float4 a0 = make_float4(0.f, 0.f, 0.f, 0.f);
  float4 a1 = make_float4(0.f, 0.f, 0.f, 0.f);

#pragma unroll 2
  for (int j = 0; j < 32; ++j) {
    const int ko = j * 64;
    float4 xv0 = *reinterpret_cast<const float4*>(xp + ko);
    float4 xv1 = *reinterpret_cast<const float4*>(xp + MODEL_DIM + ko);
    float4 w0 = *reinterpret_cast<const float4*>(wp + 0 * MODEL_DIM + ko);
    float4 w1 = *reinterpret_cast<const float4*>(wp + 1 * MODEL_DIM + ko);
    float4 w2 = *reinterpret_cast<const float4*>(wp + 2 * MODEL_DIM + ko);
    float4 w3 = *reinterpret_cast<const float4*>(wp + 3 * MODEL_DIM + ko);
    a0.x += dot4(xv0, w0); a0.y += dot4(xv0, w1);
    a0.z += dot4(xv0, w2); a0.w += dot4(xv0, w3);
    a1.x += dot4(xv1, w0); a1.y += dot4(xv1, w1);
    a1.z += dot4(xv1, w2); a1.w += dot4(xv1, w3);
  }

  // intra-16-lane butterfly sum via DPP (VALU pipe), masks {1,2,7,15}
  DPP_ADD(a0.x, 0xB1); DPP_ADD(a0.x, 0x4E); DPP_ADD(a0.x, 0x141); DPP_ADD(a0.x, 0x140);
  DPP_ADD(a0.y, 0xB1); DPP_ADD(a0.y, 0x4E); DPP_ADD(a0.y, 0x141); DPP_ADD(a0.y, 0x140);
  DPP_ADD(a0.z, 0xB1); DPP_ADD(a0.z, 0x4E); DPP_ADD(a0.z, 0x141); DPP_ADD(a0.z, 0x140);
  DPP_ADD(a0.w, 0xB1); DPP_ADD(a0.w, 0x4E); DPP_ADD(a0.w, 0x141); DPP_ADD(a0.w, 0x140);
  DPP_ADD(a1.x, 0xB1); DPP_ADD(a1.x, 0x4E); DPP_ADD(a1.x, 0x141); DPP_ADD(a1.x, 0x140);
  DPP_ADD(a1.y, 0xB1); DPP_ADD(a1.y, 0x4E); DPP_ADD(a1.y, 0x141); DPP_ADD(a1.y, 0x140);
  DPP_ADD(a1.z, 0xB1); DPP_ADD(a1.z, 0x4E); DPP_ADD(a1.z, 0x141); DPP_ADD(a1.z, 0x140);
  DPP_ADD(a1.w, 0xB1); DPP_ADD(a1.w, 0x4E); DPP_ADD(a1.w, 0x141); DPP_ADD(a1.w, 0x140);

  // group leader (kg==0) writes its 4-expert slice (no cross-group reduce!)
  if (kg == 0) {
    *reinterpret_cast<float4*>(&red[wv * 2 + 0][eg * 4]) = a0;
    *reinterpret_cast<float4*>(&red[wv * 2 + 1][eg * 4]) = a1;
  }
  __syncthreads();

  if (tid < 8) {   // lane = token within block
    const int t = b * 8 + tid;
    float logit[NUM_EXPERTS];
#pragma unroll
    for (int e = 0; e < NUM_EXPERTS; e++) logit[e] = red[tid][e];

    float m = logit[0];
#pragma unroll
    for (int e = 1; e < NUM_EXPERTS; e++) m = fmaxf(m, logit[e]);
    float gg[NUM_EXPERTS]; float z = 0.f;
#pragma unroll
    for (int e = 0; e < NUM_EXPERTS; e++) { gg[e] = expf(logit[e] - m); z += gg[e]; }
    float inv = 1.f / z;
#pragma unroll
    for (int e = 0; e < NUM_EXPERTS; e++) gg[e] *= inv;

    // top-2, ties -> lower index (matches lax.top_k / argmax)
    float v1 = gg[0], v2 = -1.f; int e1 = 0, e2 = 0;
#pragma unroll
    for (int e = 1; e < NUM_EXPERTS; e++) {
      if (gg[e] > v1) { v2 = v1; e2 = e1; v1 = gg[e]; e1 = e; }
      else if (gg[e] > v2) { v2 = gg[e]; e2 = e; }
    }
    out[W_OFF + 2 * t]     = v1;
    out[W_OFF + 2 * t + 1] = v2;
    scr[SC_E01 + t] = (uint8_t)(e1 | (e2 << 4));

    // me partial: reduce gates over the block's 8 tokens (lanes 0..7)
#pragma unroll
    for (int e = 0; e < NUM_EXPERTS; e++) {
      gg[e] += __shfl_xor(gg[e], 1, 64);
      gg[e] += __shfl_xor(gg[e], 2, 64);
      gg[e] += __shfl_xor(gg[e], 4, 64);
    }
    if (tid == 0) {
#pragma unroll
      for (int e = 0; e < NUM_EXPERTS; e++) me[b * NUM_EXPERTS + e] = gg[e];
    }
  }
}

// ============ K2: ballot counts per 64-token chunk (token order) ============
__global__ __launch_bounds__(64) void k_route(
    const uint8_t* __restrict__ scr_ro, uint8_t* __restrict__ scr) {
  const int c = blockIdx.x;
  const int lane = threadIdx.x;
  const int v = scr_ro[SC_E01 + c * 64 + lane];
  const int e1 = v & 15, e2 = v >> 4;
  int mycount = 0, myce = 0;
  for (int e = 0; e < NUM_EXPERTS; e++) {
    unsigned long long m1 = __ballot(e1 == e);
    unsigned long long m2 = __ballot(e2 == e);
    if (lane == e) { mycount = __popcll(m1 | m2); myce = __popcll(m1); }
  }
  if (lane < NUM_EXPERTS) {
    reinterpret_cast<uint16_t*>(scr + SC_CNT)[lane * NBLK + c] = (uint16_t)mycount;
    reinterpret_cast<uint16_t*>(scr + SC_CE2)[lane * NBLK + c] = (uint16_t)myce;
  }
}

// ============ K3: prefix scan + l_aux (1 block) ============
__global__ __launch_bounds__(256) void k_finish(
    uint8_t* __restrict__ scr, const float* __restrict__ me,
    float* __restrict__ out) {
  const uint16_t* counts = reinterpret_cast<const uint16_t*>(scr + SC_CNT);
  uint16_t* starts = reinterpret_cast<uint16_t*>(scr + SC_START);
  __shared__ int gs[NUM_EXPERTS][16];
  __shared__ int gstart[NUM_EXPERTS][17];
  __shared__ float sme[NUM_EXPERTS][17];
  __shared__ int sce[NUM_EXPERTS][17];
  const int tid = threadIdx.x;
  const int e = tid >> 4, grp = tid & 15;
  int s = 0;
  for (int c = grp * 16; c < grp * 16 + 16; c++) s += counts[e * NBLK + c];
  gs[e][grp] = s;
  // me / ce partial sums (parallel over 256 threads)
  {
    const uint16_t* ce2 = reinterpret_cast<const uint16_t*>(scr + SC_CE2);
    float ms = 0.f;
    for (int k = grp; k < GBLK; k += 16) ms += me[k * NUM_EXPERTS + e];
    int cs = 0;
    for (int k = grp; k < NBLK; k += 16) cs += ce2[e * NBLK + k];
    sme[e][grp] = ms; sce[e][grp] = cs;
  }
  __syncthreads();
  if (tid < NUM_EXPERTS) {
    int run = 0;
    for (int g2 = 0; g2 < 16; g2++) { gstart[tid][g2] = run; run += gs[tid][g2]; }
  }
  __syncthreads();
  int run = gstart[e][grp];
  for (int c = grp * 16; c < grp * 16 + 16; c++) {
    starts[e * NBLK + c] = (uint16_t)run;
    run += counts[e * NBLK + c];
  }
  if (tid < NUM_EXPERTS) {
    float ssum = 0.f; int ce = 0;
    for (int g2 = 0; g2 < 16; g2++) { ssum += sme[tid][g2]; ce += sce[tid][g2]; }
    float prod = (ssum * (1.0f / N_TOKENS)) * ((float)ce * (1.0f / N_TOKENS));
    prod += __shfl_xor(prod, 1, 64);
    prod += __shfl_xor(prod, 2, 64);
    prod += __shfl_xor(prod, 4, 64);
    prod += __shfl_xor(prod, 8, 64);
    if (tid == 0) out[0] = prod * (float)NUM_EXPERTS;
  }
}

// ============ K4: scatter token ids into capacity table ============
__global__ __launch_bounds__(64) void k_scatter(
    const uint8_t* __restrict__ scr, float* __restrict__ out) {
  const uint16_t* starts = reinterpret_cast<const uint16_t*>(scr + SC_START);
  const int c = blockIdx.x;
  const int lane = threadIdx.x;
  const int t = c * 64 + lane;
  const int v = scr[SC_E01 + t];
  const int e1 = v & 15, e2 = v >> 4;
  const unsigned long long below = (1ull << lane) - 1ull;
  int p1 = CAPACITY, p2 = CAPACITY;
  for (int e = 0; e < NUM_EXPERTS; e++) {
    unsigned long long m = __ballot(e1 == e) | __ballot(e2 == e);
    int r = __popcll(m & below);
    int sbase = (int)starts[e * NBLK + c];
    if (e1 == e) p1 = sbase + r;
    if (e2 == e) p2 = sbase + r;
  }
  float tf = (float)t;   // exact in fp32
  if ((unsigned)p1 < (unsigned)CAPACITY) out[IDX_OFF + e1 * CAPACITY + p1] = tf;
  if ((unsigned)p2 < (unsigned)CAPACITY) out[IDX_OFF + e2 * CAPACITY + p2] = tf;
}

// ============ K5: fill -1 in empty index slots ============
__global__ __launch_bounds__(256) void k_fill_idx(
    const uint8_t* __restrict__ scr, float* __restrict__ out) {
  const uint16_t* counts = reinterpret_cast<const uint16_t*>(scr + SC_CNT);
  const uint16_t* starts = reinterpret_cast<const uint16_t*>(scr + SC_START);
  const int i = blockIdx.x * 256 + threadIdx.x;   // 0..32767
  const int e = i >> 11;
  const int p = i & (CAPACITY - 1);
  const int tot = (int)starts[e * NBLK + NBLK - 1] + (int)counts[e * NBLK + NBLK - 1];
  if (p >= tot) out[IDX_OFF + i] = -1.0f;
}

// ============ K6 (LAST — clobbers scratch): expert_ids ============
__global__ __launch_bounds__(256) void k_eid(float* __restrict__ out) {
  const int i = blockIdx.x * 256 + threadIdx.x;   // 0..32767
  out[EID_OFF + i] = (float)(i >> 11);
}

extern "C" void kernel_launch(void* const* d_in, const int* in_sizes, int n_in,
                              void* d_out, int out_size, void* d_ws, size_t ws_size,
                              hipStream_t stream) {
  const float* x  = (const float*)d_in[0];
  const float* wg = (const float*)d_in[1];
  float* out = (float*)d_out;
  uint8_t* scr = (uint8_t*)d_out + SCR_BYTE;   // expert_ids region
  float* me = out + IDX_OFF;                   // indices region (pre-scatter)
  (void)d_ws; (void)ws_size;

  k_logits<<<GBLK, 256, 0, stream>>>(x, wg, out, me, scr);
  k_route<<<NBLK, 64, 0, stream>>>(scr, scr);
  k_finish<<<1, 256, 0, stream>>>(scr, me, out);
  k_scatter<<<NBLK, 64, 0, stream>>>(scr, out);
  k_fill_idx<<<128, 256, 0, stream>>>(scr, out);
  k_eid<<<128, 256, 0, stream>>>(out);
}

// Round 11
// 58.037 us; speedup vs baseline: 1.6894x; 1.6894x over previous
//
#include <hip/hip_runtime.h>
#include <hip/hip_bf16.h>
#include <stdint.h>

#define N_TOKENS    16384
#define MODEL_DIM   2048
#define NUM_EXPERTS 16
#define CAPACITY    2048
#define NBLK        256    // 64-token chunks for routing/ballot
#define GBLK        512    // gemv blocks (32 tokens each)
// d_out is FLOAT32. Element layout: [0]=l_aux, [1..32769)=weights[N][2],
// [32769..65537)=indices[E*CAP], [65537..98305)=expert_ids[E*CAP]
#define W_OFF       1
#define IDX_OFF     (1 + 2 * N_TOKENS)                  // 32769
#define EID_OFF     (IDX_OFF + NUM_EXPERTS * CAPACITY)  // 65537

// Scratch plan (inside d_out, race-free by same-stream ordering):
//  - me partials (float [512][16] = 32 KB) in the INDICES region: written by
//    k_logits, read by k_finish, then overwritten by k_scatter/k_fill_idx.
//  - e01/cnt/start/ce2 (40 KB) in the EXPERT_IDS region; clobbered only by
//    the FINAL kernel k_eid.
#define SCR_BYTE  (4 * EID_OFF)
#define SC_E01    0        // uint8  [16384]: e1 | (e2<<4)
#define SC_CNT    16384    // uint16 [16][256] routed counts per 64-chunk
#define SC_START  24576    // uint16 [16][256] exclusive prefix
#define SC_CE2    32768    // uint16 [16][256] argmax counts per 64-chunk

// ============ K1: GEMV logits + softmax + top2 + weights + me ============
// 512 blocks x 512 thr (8 waves; ~104 VGPR -> 4 waves/SIMD). Block b: tokens
// [b*32, b*32+32). Wave kr owns k-range [kr*256, kr*256+256); lane slice = 4
// floats, PERSISTENT w[16] in 64 VGPRs (loaded once). Per token: ONE fully
// coalesced 1KB x-load (x read exactly once chip-wide), 64 FMA, then a
// value-halving shuffle tree: fold expert-bit s with lane-bit s (s=0..3), so
// lane l ends with e = l&15 summed over 16 lanes; xor16+xor32 finish 64 lanes.
// Cross-wave reduce via LDS part[8][32][17] (pad 17: write 16 lanes/16 banks;
// read stride-17, gcd(17,32)=1 -> conflict-free).
__global__ __launch_bounds__(512) void k_logits(
    const float* __restrict__ x, const float* __restrict__ wg,
    float* __restrict__ out, float* __restrict__ me, uint8_t* __restrict__ scr)
{
  __shared__ float part[8][32][17];    // 17.4 KB
  const int tid = threadIdx.x;
  const int b = blockIdx.x;
  const int l = tid & 63;
  const int kr = tid >> 6;             // 0..7
  const int kb = kr * 256 + l * 4;

  float4 w[16];
#pragma unroll
  for (int e = 0; e < NUM_EXPERTS; ++e)
    w[e] = *reinterpret_cast<const float4*>(wg + e * MODEL_DIM + kb);

  const float* xp = x + (size_t)(b * 32) * MODEL_DIM + kb;
  float4 xva = *reinterpret_cast<const float4*>(xp);

  for (int t = 0; t < 32; ++t) {
    float4 xvb;
    if (t < 31)   // issue next token's load before the tree (latency hiding)
      xvb = *reinterpret_cast<const float4*>(xp + (size_t)(t + 1) * MODEL_DIM);

    float cur[16];
#pragma unroll
    for (int e = 0; e < NUM_EXPERTS; ++e)
      cur[e] = xva.x * w[e].x + xva.y * w[e].y + xva.z * w[e].z + xva.w * w[e].w;

    // value-halving fold: step s combines cur[2r],cur[2r+1] by lane-bit s.
    // Inductively lane l retains original index e = (l & 15).
#pragma unroll
    for (int s = 0; s < 4; ++s) {
      const int d = 1 << s;
      const bool hi = (l >> s) & 1;
#pragma unroll
      for (int r = 0; r < (16 >> (s + 1)); ++r) {
        float keep  = hi ? cur[2 * r + 1] : cur[2 * r];
        float other = hi ? cur[2 * r]     : cur[2 * r + 1];
        cur[r] = keep + __shfl_xor(other, d, 64);
      }
    }
    float v = cur[0];
    v += __shfl_xor(v, 16, 64);
    v += __shfl_xor(v, 32, 64);
    if (l < NUM_EXPERTS) part[kr][t][l] = v;
    xva = xvb;
  }
  __syncthreads();

  if (tid < 32) {   // lane = token within block
    const int tg = b * 32 + tid;
    float logit[NUM_EXPERTS];
#pragma unroll
    for (int e = 0; e < NUM_EXPERTS; ++e) {
      float s = part[0][tid][e];
#pragma unroll
      for (int k2 = 1; k2 < 8; ++k2) s += part[k2][tid][e];
      logit[e] = s;
    }

    float m = logit[0];
#pragma unroll
    for (int e = 1; e < NUM_EXPERTS; e++) m = fmaxf(m, logit[e]);
    float gg[NUM_EXPERTS]; float z = 0.f;
#pragma unroll
    for (int e = 0; e < NUM_EXPERTS; e++) { gg[e] = expf(logit[e] - m); z += gg[e]; }
    float inv = 1.f / z;
#pragma unroll
    for (int e = 0; e < NUM_EXPERTS; e++) gg[e] *= inv;

    // top-2, ties -> lower index (matches lax.top_k / argmax)
    float v1 = gg[0], v2 = -1.f; int e1 = 0, e2 = 0;
#pragma unroll
    for (int e = 1; e < NUM_EXPERTS; e++) {
      if (gg[e] > v1) { v2 = v1; e2 = e1; v1 = gg[e]; e1 = e; }
      else if (gg[e] > v2) { v2 = gg[e]; e2 = e; }
    }
    out[W_OFF + 2 * tg]     = v1;
    out[W_OFF + 2 * tg + 1] = v2;
    scr[SC_E01 + tg] = (uint8_t)(e1 | (e2 << 4));

    // me partial: reduce gates over the block's 32 tokens (lanes 0..31)
#pragma unroll
    for (int e = 0; e < NUM_EXPERTS; e++) {
      gg[e] += __shfl_xor(gg[e], 1, 64);
      gg[e] += __shfl_xor(gg[e], 2, 64);
      gg[e] += __shfl_xor(gg[e], 4, 64);
      gg[e] += __shfl_xor(gg[e], 8, 64);
      gg[e] += __shfl_xor(gg[e], 16, 64);
    }
    if (tid == 0) {
#pragma unroll
      for (int e = 0; e < NUM_EXPERTS; e++) me[b * NUM_EXPERTS + e] = gg[e];
    }
  }
}

// ============ K2: ballot counts per 64-token chunk (token order) ============
__global__ __launch_bounds__(64) void k_route(
    const uint8_t* __restrict__ scr_ro, uint8_t* __restrict__ scr) {
  const int c = blockIdx.x;
  const int lane = threadIdx.x;
  const int v = scr_ro[SC_E01 + c * 64 + lane];
  const int e1 = v & 15, e2 = v >> 4;
  int mycount = 0, myce = 0;
  for (int e = 0; e < NUM_EXPERTS; e++) {
    unsigned long long m1 = __ballot(e1 == e);
    unsigned long long m2 = __ballot(e2 == e);
    if (lane == e) { mycount = __popcll(m1 | m2); myce = __popcll(m1); }
  }
  if (lane < NUM_EXPERTS) {
    reinterpret_cast<uint16_t*>(scr + SC_CNT)[lane * NBLK + c] = (uint16_t)mycount;
    reinterpret_cast<uint16_t*>(scr + SC_CE2)[lane * NBLK + c] = (uint16_t)myce;
  }
}

// ============ K3: prefix scan + l_aux (1 block) ============
__global__ __launch_bounds__(256) void k_finish(
    uint8_t* __restrict__ scr, const float* __restrict__ me,
    float* __restrict__ out) {
  const uint16_t* counts = reinterpret_cast<const uint16_t*>(scr + SC_CNT);
  uint16_t* starts = reinterpret_cast<uint16_t*>(scr + SC_START);
  __shared__ int gs[NUM_EXPERTS][16];
  __shared__ int gstart[NUM_EXPERTS][17];
  __shared__ float sme[NUM_EXPERTS][17];
  __shared__ int sce[NUM_EXPERTS][17];
  const int tid = threadIdx.x;
  const int e = tid >> 4, grp = tid & 15;
  int s = 0;
  for (int c = grp * 16; c < grp * 16 + 16; c++) s += counts[e * NBLK + c];
  gs[e][grp] = s;
  // me / ce partial sums (parallel over 256 threads)
  {
    const uint16_t* ce2 = reinterpret_cast<const uint16_t*>(scr + SC_CE2);
    float ms = 0.f;
    for (int k = grp; k < GBLK; k += 16) ms += me[k * NUM_EXPERTS + e];
    int cs = 0;
    for (int k = grp; k < NBLK; k += 16) cs += ce2[e * NBLK + k];
    sme[e][grp] = ms; sce[e][grp] = cs;
  }
  __syncthreads();
  if (tid < NUM_EXPERTS) {
    int run = 0;
    for (int g2 = 0; g2 < 16; g2++) { gstart[tid][g2] = run; run += gs[tid][g2]; }
  }
  __syncthreads();
  int run = gstart[e][grp];
  for (int c = grp * 16; c < grp * 16 + 16; c++) {
    starts[e * NBLK + c] = (uint16_t)run;
    run += counts[e * NBLK + c];
  }
  if (tid < NUM_EXPERTS) {
    float ssum = 0.f; int ce = 0;
    for (int g2 = 0; g2 < 16; g2++) { ssum += sme[tid][g2]; ce += sce[tid][g2]; }
    float prod = (ssum * (1.0f / N_TOKENS)) * ((float)ce * (1.0f / N_TOKENS));
    prod += __shfl_xor(prod, 1, 64);
    prod += __shfl_xor(prod, 2, 64);
    prod += __shfl_xor(prod, 4, 64);
    prod += __shfl_xor(prod, 8, 64);
    if (tid == 0) out[0] = prod * (float)NUM_EXPERTS;
  }
}

// ============ K4: scatter token ids into capacity table ============
__global__ __launch_bounds__(64) void k_scatter(
    const uint8_t* __restrict__ scr, float* __restrict__ out) {
  const uint16_t* starts = reinterpret_cast<const uint16_t*>(scr + SC_START);
  const int c = blockIdx.x;
  const int lane = threadIdx.x;
  const int t = c * 64 + lane;
  const int v = scr[SC_E01 + t];
  const int e1 = v & 15, e2 = v >> 4;
  const unsigned long long below = (1ull << lane) - 1ull;
  int p1 = CAPACITY, p2 = CAPACITY;
  for (int e = 0; e < NUM_EXPERTS; e++) {
    unsigned long long m = __ballot(e1 == e) | __ballot(e2 == e);
    int r = __popcll(m & below);
    int sbase = (int)starts[e * NBLK + c];
    if (e1 == e) p1 = sbase + r;
    if (e2 == e) p2 = sbase + r;
  }
  float tf = (float)t;   // exact in fp32
  if ((unsigned)p1 < (unsigned)CAPACITY) out[IDX_OFF + e1 * CAPACITY + p1] = tf;
  if ((unsigned)p2 < (unsigned)CAPACITY) out[IDX_OFF + e2 * CAPACITY + p2] = tf;
}

// ============ K5: fill -1 in empty index slots ============
__global__ __launch_bounds__(256) void k_fill_idx(
    const uint8_t* __restrict__ scr, float* __restrict__ out) {
  const uint16_t* counts = reinterpret_cast<const uint16_t*>(scr + SC_CNT);
  const uint16_t* starts = reinterpret_cast<const uint16_t*>(scr + SC_START);
  const int i = blockIdx.x * 256 + threadIdx.x;   // 0..32767
  const int e = i >> 11;
  const int p = i & (CAPACITY - 1);
  const int tot = (int)starts[e * NBLK + NBLK - 1] + (int)counts[e * NBLK + NBLK - 1];
  if (p >= tot) out[IDX_OFF + i] = -1.0f;
}

// ============ K6 (LAST — clobbers scratch): expert_ids ============
__global__ __launch_bounds__(256) void k_eid(float* __restrict__ out) {
  const int i = blockIdx.x * 256 + threadIdx.x;   // 0..32767
  out[EID_OFF + i] = (float)(i >> 11);
}

extern "C" void kernel_launch(void* const* d_in, const int* in_sizes, int n_in,
                              void* d_out, int out_size, void* d_ws, size_t ws_size,
                              hipStream_t stream) {
  const float* x  = (const float*)d_in[0];
  const float* wg = (const float*)d_in[1];
  float* out = (float*)d_out;
  uint8_t* scr = (uint8_t*)d_out + SCR_BYTE;   // expert_ids region
  float* me = out + IDX_OFF;                   // indices region (pre-scatter)
  (void)d_ws; (void)ws_size;

  k_logits<<<GBLK, 512, 0, stream>>>(x, wg, out, me, scr);
  k_route<<<NBLK, 64, 0, stream>>>(scr, scr);
  k_finish<<<1, 256, 0, stream>>>(scr, me, out);
  k_scatter<<<NBLK, 64, 0, stream>>>(scr, out);
  k_fill_idx<<<128, 256, 0, stream>>>(scr, out);
  k_eid<<<128, 256, 0, stream>>>(out);
}

// Round 12
// 52.111 us; speedup vs baseline: 1.8815x; 1.1137x over previous
//
#include <hip/hip_runtime.h>
#include <hip/hip_bf16.h>
#include <stdint.h>

#define N_TOKENS    16384
#define MODEL_DIM   2048
#define NUM_EXPERTS 16
#define CAPACITY    2048
#define NBLK2       512    // 32-token half-chunks (== gemv blocks)
#define NBLK        256    // 64-token chunks for scatter
#define GBLK        512    // gemv blocks (32 tokens each)
// d_out is FLOAT32. [0]=l_aux, [1..32769)=weights[N][2],
// [32769..65537)=indices[E*CAP], [65537..98305)=expert_ids[E*CAP]
#define W_OFF       1
#define IDX_OFF     (1 + 2 * N_TOKENS)                  // 32769
#define EID_OFF     (IDX_OFF + NUM_EXPERTS * CAPACITY)  // 65537

// Scratch in d_ws (~512 MB per harness poison evidence; we use ~100 KB).
// All regions fully rewritten by this call's kernels before being read.
#define SC_E01    0        // uint8  [16384]: e1 | (e2<<4)
#define SC_CNTH   16384    // uint16 [16][512] routed counts per half-chunk
#define SC_CEH    32768    // uint16 [16][512] argmax counts per half-chunk
#define SC_START  49152    // uint16 [16][256] exclusive prefix per 64-chunk
#define SC_TOT    57344    // uint16 [16] totals
#define SC_ME     57408    // float  [512][16] gate sums per gemv block (pad to 4B align: 57408%4==0)

// Cross-lane helpers. DPP quad_perm: xor1=0xB1, xor2=0x4E (VALU pipe).
// ds_swizzle BitMode imm: xor4=0x101F, xor8=0x201F, xor16=0x401F (DS pipe,
// immediate pattern -> no per-lane address math).
#define DPPX(v, ctrl) __int_as_float(__builtin_amdgcn_update_dpp(             \
    0, __float_as_int(v), (ctrl), 0xF, 0xF, true))
#define SWZ(v, off) __int_as_float(__builtin_amdgcn_ds_swizzle(               \
    __float_as_int(v), (off)))

// ============ K1: GEMV logits + softmax + top2 + weights + counts + me ======
// 512 blocks x 512 thr (8 waves). Block b: tokens [b*32, b*32+32). Wave kr
// owns k-range [kr*256, kr*256+256); lane slice 4 floats; PERSISTENT w[16]
// in 64 VGPRs. Per token: ONE coalesced 1KB x-load (x read once chip-wide),
// 64 FMA, then the value-halving fold tree (identical arithmetic to the
// verified absmax-0.0 version): expert-bit s folds with lane-bit s; steps
// 0,1 via DPP (VALU), steps 2,3 + xor16 via ds_swizzle, xor32 via shfl.
// Epilogue (32 lanes): softmax/top2/weights/e01 + ballots -> per-half-chunk
// counts (replaces the old k_route kernel) + me partials.
__global__ __launch_bounds__(512) void k_logits(
    const float* __restrict__ x, const float* __restrict__ wg,
    float* __restrict__ out, uint8_t* __restrict__ ws)
{
  __shared__ float part[8][32][17];    // 17.4 KB
  const int tid = threadIdx.x;
  const int b = blockIdx.x;
  const int l = tid & 63;
  const int kr = tid >> 6;             // 0..7
  const int kb = kr * 256 + l * 4;

  float4 w[16];
#pragma unroll
  for (int e = 0; e < NUM_EXPERTS; ++e)
    w[e] = *reinterpret_cast<const float4*>(wg + e * MODEL_DIM + kb);

  const float* xp = x + (size_t)(b * 32) * MODEL_DIM + kb;
  float4 xva = *reinterpret_cast<const float4*>(xp);

  const bool h0 = l & 1, h1 = l & 2, h2 = l & 4, h3 = l & 8;

  for (int t = 0; t < 32; ++t) {
    float4 xvb;
    if (t < 31)
      xvb = *reinterpret_cast<const float4*>(xp + (size_t)(t + 1) * MODEL_DIM);

    float cur[16];
#pragma unroll
    for (int e = 0; e < NUM_EXPERTS; ++e)
      cur[e] = xva.x * w[e].x + xva.y * w[e].y + xva.z * w[e].z + xva.w * w[e].w;

    // fold expert-bit0 with lane-bit0 (DPP xor1)
#pragma unroll
    for (int r = 0; r < 8; ++r) {
      float k = h0 ? cur[2 * r + 1] : cur[2 * r];
      float o = h0 ? cur[2 * r]     : cur[2 * r + 1];
      cur[r] = k + DPPX(o, 0xB1);
    }
    // fold expert-bit1 with lane-bit1 (DPP xor2)
#pragma unroll
    for (int r = 0; r < 4; ++r) {
      float k = h1 ? cur[2 * r + 1] : cur[2 * r];
      float o = h1 ? cur[2 * r]     : cur[2 * r + 1];
      cur[r] = k + DPPX(o, 0x4E);
    }
    // fold expert-bit2 with lane-bit2 (ds_swizzle xor4)
#pragma unroll
    for (int r = 0; r < 2; ++r) {
      float k = h2 ? cur[2 * r + 1] : cur[2 * r];
      float o = h2 ? cur[2 * r]     : cur[2 * r + 1];
      cur[r] = k + SWZ(o, 0x101F);
    }
    // fold expert-bit3 with lane-bit3 (ds_swizzle xor8)
    float v;
    {
      float k = h3 ? cur[1] : cur[0];
      float o = h3 ? cur[0] : cur[1];
      v = k + SWZ(o, 0x201F);
    }
    v += SWZ(v, 0x401F);          // xor16
    v += __shfl_xor(v, 32, 64);   // xor32
    if (l < NUM_EXPERTS) part[kr][t][l] = v;
    xva = xvb;
  }
  __syncthreads();

  if (tid < 32) {   // lane = token within block
    const int tg = b * 32 + tid;
    float logit[NUM_EXPERTS];
#pragma unroll
    for (int e = 0; e < NUM_EXPERTS; ++e) {
      float s = part[0][tid][e];
#pragma unroll
      for (int k2 = 1; k2 < 8; ++k2) s += part[k2][tid][e];
      logit[e] = s;
    }

    float m = logit[0];
#pragma unroll
    for (int e = 1; e < NUM_EXPERTS; e++) m = fmaxf(m, logit[e]);
    float gg[NUM_EXPERTS]; float z = 0.f;
#pragma unroll
    for (int e = 0; e < NUM_EXPERTS; e++) { gg[e] = expf(logit[e] - m); z += gg[e]; }
    float inv = 1.f / z;
#pragma unroll
    for (int e = 0; e < NUM_EXPERTS; e++) gg[e] *= inv;

    // top-2, ties -> lower index (matches lax.top_k / argmax)
    float v1 = gg[0], v2 = -1.f; int e1 = 0, e2 = 0;
#pragma unroll
    for (int e = 1; e < NUM_EXPERTS; e++) {
      if (gg[e] > v1) { v2 = v1; e2 = e1; v1 = gg[e]; e1 = e; }
      else if (gg[e] > v2) { v2 = gg[e]; e2 = e; }
    }
    out[W_OFF + 2 * tg]     = v1;
    out[W_OFF + 2 * tg + 1] = v2;
    ws[SC_E01 + tg] = (uint8_t)(e1 | (e2 << 4));

    // per-half-chunk routed counts + argmax counts (32 active lanes)
    int mycount = 0, myce = 0;
    for (int e = 0; e < NUM_EXPERTS; e++) {
      unsigned long long m1 = __ballot(e1 == e);
      unsigned long long m2 = __ballot(e2 == e);
      if (tid == e) { mycount = __popcll(m1 | m2); myce = __popcll(m1); }
    }
    if (tid < NUM_EXPERTS) {
      reinterpret_cast<uint16_t*>(ws + SC_CNTH)[tid * NBLK2 + b] = (uint16_t)mycount;
      reinterpret_cast<uint16_t*>(ws + SC_CEH)[tid * NBLK2 + b] = (uint16_t)myce;
    }

    // me partial over the block's 32 tokens
#pragma unroll
    for (int e = 0; e < NUM_EXPERTS; e++) {
      gg[e] += __shfl_xor(gg[e], 1, 64);
      gg[e] += __shfl_xor(gg[e], 2, 64);
      gg[e] += __shfl_xor(gg[e], 4, 64);
      gg[e] += __shfl_xor(gg[e], 8, 64);
      gg[e] += __shfl_xor(gg[e], 16, 64);
    }
    if (tid == 0) {
      float* mp = reinterpret_cast<float*>(ws + SC_ME);
#pragma unroll
      for (int e = 0; e < NUM_EXPERTS; e++) mp[b * NUM_EXPERTS + e] = gg[e];
    }
  }
}

// ============ K2: prefix scan + totals + l_aux (1 block) ============
__global__ __launch_bounds__(256) void k_finish(
    uint8_t* __restrict__ ws, float* __restrict__ out) {
  const uint16_t* cnth = reinterpret_cast<const uint16_t*>(ws + SC_CNTH);
  uint16_t* starts = reinterpret_cast<uint16_t*>(ws + SC_START);
  uint16_t* totw = reinterpret_cast<uint16_t*>(ws + SC_TOT);
  __shared__ int gs[NUM_EXPERTS][16];
  __shared__ int gstart[NUM_EXPERTS][17];
  __shared__ float sme[NUM_EXPERTS][17];
  __shared__ int sce[NUM_EXPERTS][17];
  const int tid = threadIdx.x;
  const int e = tid >> 4, grp = tid & 15;
  int s = 0;
  for (int hc = grp * 32; hc < grp * 32 + 32; hc++) s += cnth[e * NBLK2 + hc];
  gs[e][grp] = s;
  {
    const float* mepart = reinterpret_cast<const float*>(ws + SC_ME);
    const uint16_t* ceh = reinterpret_cast<const uint16_t*>(ws + SC_CEH);
    float ms = 0.f; int cs = 0;
    for (int k = grp; k < NBLK2; k += 16) {
      ms += mepart[k * NUM_EXPERTS + e];
      cs += ceh[e * NBLK2 + k];
    }
    sme[e][grp] = ms; sce[e][grp] = cs;
  }
  __syncthreads();
  if (tid < NUM_EXPERTS) {
    int run = 0;
    for (int g2 = 0; g2 < 16; g2++) { gstart[tid][g2] = run; run += gs[tid][g2]; }
  }
  __syncthreads();
  int run = gstart[e][grp];
  for (int c = grp * 16; c < grp * 16 + 16; c++) {
    starts[e * NBLK + c] = (uint16_t)run;
    run += cnth[e * NBLK2 + 2 * c] + cnth[e * NBLK2 + 2 * c + 1];
  }
  if (grp == 15) totw[e] = (uint16_t)run;   // full total for expert e
  if (tid < NUM_EXPERTS) {
    float ssum = 0.f; int ce = 0;
    for (int g2 = 0; g2 < 16; g2++) { ssum += sme[tid][g2]; ce += sce[tid][g2]; }
    float prod = (ssum * (1.0f / N_TOKENS)) * ((float)ce * (1.0f / N_TOKENS));
    prod += __shfl_xor(prod, 1, 64);
    prod += __shfl_xor(prod, 2, 64);
    prod += __shfl_xor(prod, 4, 64);
    prod += __shfl_xor(prod, 8, 64);
    if (tid == 0) out[0] = prod * (float)NUM_EXPERTS;
  }
}

// ============ K3: scatter + fill(-1) + expert_ids (fused) ============
// 256 blocks x 192 thr. Wave 0 (tid<64): scatter chunk b's token ids
// (writes only slots < tot[e]). tids 64..191: slots b*128+(tid-64):
// write -1 where slot >= tot[e] (disjoint from scatter) and expert_ids.
__global__ __launch_bounds__(192) void k_scatter_fill(
    const uint8_t* __restrict__ ws, float* __restrict__ out) {
  const uint16_t* starts = reinterpret_cast<const uint16_t*>(ws + SC_START);
  const uint16_t* totw = reinterpret_cast<const uint16_t*>(ws + SC_TOT);
  const int tid = threadIdx.x;
  const int b = blockIdx.x;
  if (tid < 64) {
    const int t = b * 64 + tid;
    const int v = ws[SC_E01 + t];
    const int e1 = v & 15, e2 = v >> 4;
    const unsigned long long below = (1ull << tid) - 1ull;
    int p1 = CAPACITY, p2 = CAPACITY;
    for (int e = 0; e < NUM_EXPERTS; e++) {
      unsigned long long m = __ballot(e1 == e) | __ballot(e2 == e);
      int r = __popcll(m & below);
      int sbase = (int)starts[e * NBLK + b];
      if (e1 == e) p1 = sbase + r;
      if (e2 == e) p2 = sbase + r;
    }
    float tf = (float)t;   // exact in fp32
    if ((unsigned)p1 < (unsigned)CAPACITY) out[IDX_OFF + e1 * CAPACITY + p1] = tf;
    if ((unsigned)p2 < (unsigned)CAPACITY) out[IDX_OFF + e2 * CAPACITY + p2] = tf;
  } else {
    const int slot = b * 128 + (tid - 64);   // 0..32767
    const int e = slot >> 11;
    const int p = slot & (CAPACITY - 1);
    if (p >= (int)totw[e]) out[IDX_OFF + slot] = -1.0f;
    out[EID_OFF + slot] = (float)e;
  }
}

extern "C" void kernel_launch(void* const* d_in, const int* in_sizes, int n_in,
                              void* d_out, int out_size, void* d_ws, size_t ws_size,
                              hipStream_t stream) {
  const float* x  = (const float*)d_in[0];
  const float* wg = (const float*)d_in[1];
  float* out = (float*)d_out;
  uint8_t* ws = (uint8_t*)d_ws;

  k_logits<<<GBLK, 512, 0, stream>>>(x, wg, out, ws);
  k_finish<<<1, 256, 0, stream>>>(ws, out);
  k_scatter_fill<<<NBLK, 192, 0, stream>>>(ws, out);
}

// Round 13
// 49.794 us; speedup vs baseline: 1.9691x; 1.0465x over previous
//
#include <hip/hip_runtime.h>
#include <hip/hip_bf16.h>
#include <stdint.h>

#define N_TOKENS    16384
#define MODEL_DIM   2048
#define NUM_EXPERTS 16
#define CAPACITY    2048
#define NBLK2       512    // 32-token half-chunks (== gemv blocks)
#define NBLK        256    // 64-token chunks for scatter
#define GBLK        512    // gemv blocks (32 tokens each)
// d_out is FLOAT32. [0]=l_aux, [1..32769)=weights[N][2],
// [32769..65537)=indices[E*CAP], [65537..98305)=expert_ids[E*CAP]
#define W_OFF       1
#define IDX_OFF     (1 + 2 * N_TOKENS)                  // 32769
#define EID_OFF     (IDX_OFF + NUM_EXPERTS * CAPACITY)  // 65537

// Scratch in d_ws (512 MB; we use ~90 KB). All regions fully (re)written by
// k_logits each call before k_tail reads them.
#define SC_E01    0        // uint8  [16384]: e1 | (e2<<4)
#define SC_CNTH   16384    // uint16 [16][512] routed counts per half-chunk
#define SC_CEH    32768    // uint16 [16][512] argmax counts per half-chunk
#define SC_ME     49152    // float  [512][16] gate sums per gemv block

// Cross-lane helpers. DPP quad_perm xor1=0xB1, xor2=0x4E; row_ror:8=0x128
// implements xor8 within 16-lane rows ((i+8)&15 == i^8) on the VALU pipe.
// ds_swizzle BitMode imm: xor4=0x101F, xor16=0x401F (DS pipe).
#define DPPX(v, ctrl) __int_as_float(__builtin_amdgcn_update_dpp(             \
    0, __float_as_int(v), (ctrl), 0xF, 0xF, true))
#define SWZ(v, off) __int_as_float(__builtin_amdgcn_ds_swizzle(               \
    __float_as_int(v), (off)))

// ============ K1: GEMV logits + softmax + top2 + weights + counts + me ======
// 512 blocks x 512 thr (8 waves, 2 blocks/CU). Block b: tokens [b*32,+32).
// Wave kr owns k-range [kr*256,+256); lane slice 4 floats; PERSISTENT w[16]
// in 64 VGPRs. Per token: ONE coalesced 1KB x-load (x read once chip-wide,
// 2-deep prefetch -> ~1900cy slack vs ~900cy HBM latency), 64 FMA, then the
// value-halving fold tree (arithmetic IDENTICAL to the absmax-0.0 version):
// expert-bit s folds with lane-bit s; xor1/xor2/xor8 on DPP (VALU pipe),
// xor4/xor16 via ds_swizzle, xor32 via shfl.
__global__ __launch_bounds__(512) void k_logits(
    const float* __restrict__ x, const float* __restrict__ wg,
    float* __restrict__ out, uint8_t* __restrict__ ws)
{
  __shared__ float part[8][32][17];    // 17.4 KB
  const int tid = threadIdx.x;
  const int b = blockIdx.x;
  const int l = tid & 63;
  const int kr = tid >> 6;             // 0..7
  const int kb = kr * 256 + l * 4;

  float4 w[16];
#pragma unroll
  for (int e = 0; e < NUM_EXPERTS; ++e)
    w[e] = *reinterpret_cast<const float4*>(wg + e * MODEL_DIM + kb);

  const float* xp = x + (size_t)(b * 32) * MODEL_DIM + kb;
  float4 xva = *reinterpret_cast<const float4*>(xp);
  float4 xvb = *reinterpret_cast<const float4*>(xp + MODEL_DIM);

  const bool h0 = l & 1, h1 = l & 2, h2 = l & 4, h3 = l & 8;

  for (int t = 0; t < 32; ++t) {
    float4 xvc;
    if (t < 30)
      xvc = *reinterpret_cast<const float4*>(xp + (size_t)(t + 2) * MODEL_DIM);

    float cur[16];
#pragma unroll
    for (int e = 0; e < NUM_EXPERTS; ++e)
      cur[e] = xva.x * w[e].x + xva.y * w[e].y + xva.z * w[e].z + xva.w * w[e].w;

    // fold expert-bit0 with lane-bit0 (DPP xor1)
#pragma unroll
    for (int r = 0; r < 8; ++r) {
      float k = h0 ? cur[2 * r + 1] : cur[2 * r];
      float o = h0 ? cur[2 * r]     : cur[2 * r + 1];
      cur[r] = k + DPPX(o, 0xB1);
    }
    // fold expert-bit1 with lane-bit1 (DPP xor2)
#pragma unroll
    for (int r = 0; r < 4; ++r) {
      float k = h1 ? cur[2 * r + 1] : cur[2 * r];
      float o = h1 ? cur[2 * r]     : cur[2 * r + 1];
      cur[r] = k + DPPX(o, 0x4E);
    }
    // fold expert-bit2 with lane-bit2 (ds_swizzle xor4)
#pragma unroll
    for (int r = 0; r < 2; ++r) {
      float k = h2 ? cur[2 * r + 1] : cur[2 * r];
      float o = h2 ? cur[2 * r]     : cur[2 * r + 1];
      cur[r] = k + SWZ(o, 0x101F);
    }
    // fold expert-bit3 with lane-bit3 (DPP row_ror:8 == xor8)
    float v;
    {
      float k = h3 ? cur[1] : cur[0];
      float o = h3 ? cur[0] : cur[1];
      v = k + DPPX(o, 0x128);
    }
    v += SWZ(v, 0x401F);          // xor16
    v += __shfl_xor(v, 32, 64);   // xor32
    if (l < NUM_EXPERTS) part[kr][t][l] = v;
    xva = xvb; xvb = xvc;
  }
  __syncthreads();

  if (tid < 32) {   // lane = token within block
    const int tg = b * 32 + tid;
    float logit[NUM_EXPERTS];
#pragma unroll
    for (int e = 0; e < NUM_EXPERTS; ++e) {
      float s = part[0][tid][e];
#pragma unroll
      for (int k2 = 1; k2 < 8; ++k2) s += part[k2][tid][e];
      logit[e] = s;
    }

    float m = logit[0];
#pragma unroll
    for (int e = 1; e < NUM_EXPERTS; e++) m = fmaxf(m, logit[e]);
    float gg[NUM_EXPERTS]; float z = 0.f;
#pragma unroll
    for (int e = 0; e < NUM_EXPERTS; e++) { gg[e] = expf(logit[e] - m); z += gg[e]; }
    float inv = 1.f / z;
#pragma unroll
    for (int e = 0; e < NUM_EXPERTS; e++) gg[e] *= inv;

    // top-2, ties -> lower index (matches lax.top_k / argmax)
    float v1 = gg[0], v2 = -1.f; int e1 = 0, e2 = 0;
#pragma unroll
    for (int e = 1; e < NUM_EXPERTS; e++) {
      if (gg[e] > v1) { v2 = v1; e2 = e1; v1 = gg[e]; e1 = e; }
      else if (gg[e] > v2) { v2 = gg[e]; e2 = e; }
    }
    out[W_OFF + 2 * tg]     = v1;
    out[W_OFF + 2 * tg + 1] = v2;
    ws[SC_E01 + tg] = (uint8_t)(e1 | (e2 << 4));

    // per-half-chunk routed counts + argmax counts (32 active lanes)
    int mycount = 0, myce = 0;
    for (int e = 0; e < NUM_EXPERTS; e++) {
      unsigned long long m1 = __ballot(e1 == e);
      unsigned long long m2 = __ballot(e2 == e);
      if (tid == e) { mycount = __popcll(m1 | m2); myce = __popcll(m1); }
    }
    if (tid < NUM_EXPERTS) {
      reinterpret_cast<uint16_t*>(ws + SC_CNTH)[tid * NBLK2 + b] = (uint16_t)mycount;
      reinterpret_cast<uint16_t*>(ws + SC_CEH)[tid * NBLK2 + b] = (uint16_t)myce;
    }

    // me partial over the block's 32 tokens
#pragma unroll
    for (int e = 0; e < NUM_EXPERTS; e++) {
      gg[e] += __shfl_xor(gg[e], 1, 64);
      gg[e] += __shfl_xor(gg[e], 2, 64);
      gg[e] += __shfl_xor(gg[e], 4, 64);
      gg[e] += __shfl_xor(gg[e], 8, 64);
      gg[e] += __shfl_xor(gg[e], 16, 64);
    }
    if (tid == 0) {
      float* mp = reinterpret_cast<float*>(ws + SC_ME);
#pragma unroll
      for (int e = 0; e < NUM_EXPERTS; e++) mp[b * NUM_EXPERTS + e] = gg[e];
    }
  }
}

// ============ K2: per-block prefix + scatter + fill + eid + l_aux ============
// 257 blocks x 192 thr. Blocks 0..255: wave 0 computes this chunk's 16-expert
// exclusive prefix (from the shared 16KB cnth table; limit=2b is even so u16
// pairs never split) then ballot-scatters chunk b's 64 tokens; waves 1-2 fill
// -1 (slots >= tot) and expert_ids for slots [b*128, b*128+128) (expert b/16
// uniform). Block 256: l_aux. No atomics; fully deterministic.
__global__ __launch_bounds__(192) void k_tail(
    const uint8_t* __restrict__ ws, float* __restrict__ out) {
  __shared__ int sstart[NUM_EXPERTS];
  __shared__ int stot[NUM_EXPERTS];
  const int tid = threadIdx.x;
  const int b = blockIdx.x;

  if (b == 256) {   // l_aux
    __shared__ float sme2[12][NUM_EXPERTS];
    __shared__ int sce2[12][NUM_EXPERTS];
    const float* me = reinterpret_cast<const float*>(ws + SC_ME);
    const uint16_t* ceh = reinterpret_cast<const uint16_t*>(ws + SC_CEH);
    const int e = tid & 15, grp = tid >> 4;   // 12 groups
    float ms = 0.f; int cs = 0;
    for (int k = grp; k < NBLK2; k += 12) {
      ms += me[k * NUM_EXPERTS + e];
      cs += ceh[e * NBLK2 + k];
    }
    sme2[grp][e] = ms; sce2[grp][e] = cs;
    __syncthreads();
    if (tid < NUM_EXPERTS) {
      float ssum = 0.f; int ce = 0;
#pragma unroll
      for (int g2 = 0; g2 < 12; g2++) { ssum += sme2[g2][tid]; ce += sce2[g2][tid]; }
      float prod = (ssum * (1.0f / N_TOKENS)) * ((float)ce * (1.0f / N_TOKENS));
      prod += __shfl_xor(prod, 1, 64);
      prod += __shfl_xor(prod, 2, 64);
      prod += __shfl_xor(prod, 4, 64);
      prod += __shfl_xor(prod, 8, 64);
      if (tid == 0) out[0] = prod * (float)NUM_EXPERTS;
    }
    return;
  }

  // ---- blocks 0..255 ----
  if (tid < 64) {   // per-block prefix: lane (e = tid>>2, q = tid&3)
    const int e = tid >> 2, q = tid & 3;
    const uint32_t* row =
        reinterpret_cast<const uint32_t*>(ws + SC_CNTH) + e * (NBLK2 / 2) + q * 64;
    const int limit = 2 * b;          // even -> u16 pairs never split
    int s_lt = 0, s_all = 0;
    for (int wd = 0; wd < 64; ++wd) {
      uint32_t v = row[wd];
      int pair = (int)(v & 0xFFFF) + (int)(v >> 16);
      s_all += pair;
      if (q * 128 + 2 * wd < limit) s_lt += pair;
    }
    s_lt += __shfl_xor(s_lt, 1, 64);  s_lt += __shfl_xor(s_lt, 2, 64);
    s_all += __shfl_xor(s_all, 1, 64); s_all += __shfl_xor(s_all, 2, 64);
    if (q == 0) { sstart[e] = s_lt; stot[e] = s_all; }
  }
  __syncthreads();

  if (tid < 64) {   // wave 0: ballot scatter (lane = token in chunk b)
    const int t = b * 64 + tid;
    const int v = ws[SC_E01 + t];
    const int e1 = v & 15, e2 = v >> 4;
    const unsigned long long below = (1ull << tid) - 1ull;
    int p1 = CAPACITY, p2 = CAPACITY;
    for (int e = 0; e < NUM_EXPERTS; e++) {
      unsigned long long m = __ballot(e1 == e) | __ballot(e2 == e);
      int r = __popcll(m & below);
      int sbase = sstart[e];
      if (e1 == e) p1 = sbase + r;
      if (e2 == e) p2 = sbase + r;
    }
    float tf = (float)t;   // exact in fp32
    if ((unsigned)p1 < (unsigned)CAPACITY) out[IDX_OFF + e1 * CAPACITY + p1] = tf;
    if ((unsigned)p2 < (unsigned)CAPACITY) out[IDX_OFF + e2 * CAPACITY + p2] = tf;
  } else {          // waves 1-2: fill -1 + expert_ids for 128 slots
    const int slot = b * 128 + (tid - 64);   // 0..32767
    const int e = slot >> 11;                // == b/16, uniform per block
    const int p = slot & (CAPACITY - 1);
    if (p >= stot[e]) out[IDX_OFF + slot] = -1.0f;
    out[EID_OFF + slot] = (float)e;
  }
}

extern "C" void kernel_launch(void* const* d_in, const int* in_sizes, int n_in,
                              void* d_out, int out_size, void* d_ws, size_t ws_size,
                              hipStream_t stream) {
  const float* x  = (const float*)d_in[0];
  const float* wg = (const float*)d_in[1];
  float* out = (float*)d_out;
  uint8_t* ws = (uint8_t*)d_ws;

  k_logits<<<GBLK, 512, 0, stream>>>(x, wg, out, ws);
  k_tail<<<257, 192, 0, stream>>>(ws, out);
}

// Round 14
// 48.836 us; speedup vs baseline: 2.0077x; 1.0196x over previous
//
#include <hip/hip_runtime.h>
#include <hip/hip_bf16.h>
#include <stdint.h>

#define N_TOKENS    16384
#define MODEL_DIM   2048
#define NUM_EXPERTS 16
#define CAPACITY    2048
#define NBLK2       512    // 32-token half-chunks (== gemv blocks)
#define NBLK        256    // 64-token chunks for scatter
#define GBLK        512    // gemv blocks (32 tokens each)
// d_out is FLOAT32. [0]=l_aux, [1..32769)=weights[N][2],
// [32769..65537)=indices[E*CAP], [65537..98305)=expert_ids[E*CAP]
#define W_OFF       1
#define IDX_OFF     (1 + 2 * N_TOKENS)                  // 32769
#define EID_OFF     (IDX_OFF + NUM_EXPERTS * CAPACITY)  // 65537

// Scratch in d_ws (512 MB; we use ~90 KB). All regions fully (re)written by
// k_logits each call before k_tail reads them.
#define SC_E01    0        // uint8  [16384]: e1 | (e2<<4)
#define SC_CNTH   16384    // uint16 [16][512] routed counts per half-chunk
#define SC_CEH    32768    // uint16 [16][512] argmax counts per half-chunk
#define SC_ME     49152    // float  [512][16] gate sums per gemv block

// Cross-lane helpers. DPP quad_perm xor1=0xB1, xor2=0x4E; row_ror:8=0x128
// (== lane^8 within 16-lane rows). ds_swizzle BitMode: xor4=0x101F,
// xor16=0x401F (within 32-lane halves).
#define DPPX(v, ctrl) __int_as_float(__builtin_amdgcn_update_dpp(             \
    0, __float_as_int(v), (ctrl), 0xF, 0xF, true))
#define SWZ(v, off) __int_as_float(__builtin_amdgcn_ds_swizzle(               \
    __float_as_int(v), (off)))

// ============ K1: GEMV logits + softmax + top2 + weights + counts + me ======
// 512 blocks x 512 thr (8 waves, 2 blocks/CU, ~105 VGPR -> 4 waves/SIMD).
// Block b: tokens [b*32,+32). Wave kr owns k-range [kr*256,+256); lane slice
// 4 floats; PERSISTENT w[16] in 64 VGPRs. ROTATED-EXPERT layout: slot i on
// lane l holds expert i^(l&15)  ->  every fold is a bare
// cur[r] = cur[2r] + shfl_xor(cur[2r+1], 1<<s): NO cndmask selects.
// After the 4 folds lane l holds expert l&15 (16-lane k-sum); xor16 swizzle
// gives 32-lane-half sums; the two halves store separate partials and the
// epilogue sums 16 values/expert. Per token: ONE coalesced 1KB x-load
// (x read once chip-wide, 2-deep prefetch), 64 FMA, 15 select-free folds.
__global__ __launch_bounds__(512) void k_logits(
    const float* __restrict__ x, const float* __restrict__ wg,
    float* __restrict__ out, uint8_t* __restrict__ ws)
{
  __shared__ float part[8][32][2][17];   // 34.8 KB
  const int tid = threadIdx.x;
  const int b = blockIdx.x;
  const int l = tid & 63;
  const int kr = tid >> 6;             // 0..7
  const int kb = kr * 256 + l * 4;
  const int rot = l & 15;

  float4 w[16];
#pragma unroll
  for (int i = 0; i < NUM_EXPERTS; ++i)
    w[i] = *reinterpret_cast<const float4*>(wg + (size_t)((i ^ rot) * MODEL_DIM) + kb);

  const float* xp = x + (size_t)(b * 32) * MODEL_DIM + kb;
  float4 xva = *reinterpret_cast<const float4*>(xp);
  float4 xvb = *reinterpret_cast<const float4*>(xp + MODEL_DIM);

#pragma unroll 2
  for (int t = 0; t < 32; ++t) {
    float4 xvc;
    if (t < 30)
      xvc = *reinterpret_cast<const float4*>(xp + (size_t)(t + 2) * MODEL_DIM);

    float cur[16];
#pragma unroll
    for (int i = 0; i < NUM_EXPERTS; ++i)
      cur[i] = xva.x * w[i].x + xva.y * w[i].y + xva.z * w[i].z + xva.w * w[i].w;

    // select-free rotated folds: s=0 (DPP xor1)
#pragma unroll
    for (int r = 0; r < 8; ++r) cur[r] = cur[2 * r] + DPPX(cur[2 * r + 1], 0xB1);
    // s=1 (DPP xor2)
#pragma unroll
    for (int r = 0; r < 4; ++r) cur[r] = cur[2 * r] + DPPX(cur[2 * r + 1], 0x4E);
    // s=2 (ds_swizzle xor4)
#pragma unroll
    for (int r = 0; r < 2; ++r) cur[r] = cur[2 * r] + SWZ(cur[2 * r + 1], 0x101F);
    // s=3 (DPP row_ror:8 == xor8 within 16-lane rows)
    float v = cur[0] + DPPX(cur[1], 0x128);
    // 16-lane group sum -> 32-lane half sum
    v += SWZ(v, 0x401F);          // xor16 (within each 32-half)
    if ((l & 31) < 16) part[kr][t][l >> 5][l & 15] = v;
    xva = xvb; xvb = xvc;
  }
  __syncthreads();

  if (tid < 32) {   // lane = token within block
    const int tg = b * 32 + tid;
    float logit[NUM_EXPERTS];
#pragma unroll
    for (int e4 = 0; e4 < 4; ++e4) {
      float4 s = *reinterpret_cast<const float4*>(&part[0][tid][0][e4 * 4]);
#pragma unroll
      for (int k2 = 0; k2 < 8; ++k2) {
#pragma unroll
        for (int h = 0; h < 2; ++h) {
          if (k2 == 0 && h == 0) continue;
          float4 p = *reinterpret_cast<const float4*>(&part[k2][tid][h][e4 * 4]);
          s.x += p.x; s.y += p.y; s.z += p.z; s.w += p.w;
        }
      }
      logit[e4 * 4 + 0] = s.x; logit[e4 * 4 + 1] = s.y;
      logit[e4 * 4 + 2] = s.z; logit[e4 * 4 + 3] = s.w;
    }

    float m = logit[0];
#pragma unroll
    for (int e = 1; e < NUM_EXPERTS; e++) m = fmaxf(m, logit[e]);
    float gg[NUM_EXPERTS]; float z = 0.f;
#pragma unroll
    for (int e = 0; e < NUM_EXPERTS; e++) { gg[e] = expf(logit[e] - m); z += gg[e]; }
    float inv = 1.f / z;
#pragma unroll
    for (int e = 0; e < NUM_EXPERTS; e++) gg[e] *= inv;

    // top-2, ties -> lower index (matches lax.top_k / argmax)
    float v1 = gg[0], v2 = -1.f; int e1 = 0, e2 = 0;
#pragma unroll
    for (int e = 1; e < NUM_EXPERTS; e++) {
      if (gg[e] > v1) { v2 = v1; e2 = e1; v1 = gg[e]; e1 = e; }
      else if (gg[e] > v2) { v2 = gg[e]; e2 = e; }
    }
    out[W_OFF + 2 * tg]     = v1;
    out[W_OFF + 2 * tg + 1] = v2;
    ws[SC_E01 + tg] = (uint8_t)(e1 | (e2 << 4));

    // per-half-chunk routed counts + argmax counts (32 active lanes)
    int mycount = 0, myce = 0;
    for (int e = 0; e < NUM_EXPERTS; e++) {
      unsigned long long m1 = __ballot(e1 == e);
      unsigned long long m2 = __ballot(e2 == e);
      if (tid == e) { mycount = __popcll(m1 | m2); myce = __popcll(m1); }
    }
    if (tid < NUM_EXPERTS) {
      reinterpret_cast<uint16_t*>(ws + SC_CNTH)[tid * NBLK2 + b] = (uint16_t)mycount;
      reinterpret_cast<uint16_t*>(ws + SC_CEH)[tid * NBLK2 + b] = (uint16_t)myce;
    }

    // me partial over the block's 32 tokens
#pragma unroll
    for (int e = 0; e < NUM_EXPERTS; e++) {
      gg[e] += __shfl_xor(gg[e], 1, 64);
      gg[e] += __shfl_xor(gg[e], 2, 64);
      gg[e] += __shfl_xor(gg[e], 4, 64);
      gg[e] += __shfl_xor(gg[e], 8, 64);
      gg[e] += __shfl_xor(gg[e], 16, 64);
    }
    if (tid == 0) {
      float* mp = reinterpret_cast<float*>(ws + SC_ME);
#pragma unroll
      for (int e = 0; e < NUM_EXPERTS; e++) mp[b * NUM_EXPERTS + e] = gg[e];
    }
  }
}

// ============ K2: per-block prefix + scatter + fill + eid + l_aux ============
__global__ __launch_bounds__(192) void k_tail(
    const uint8_t* __restrict__ ws, float* __restrict__ out) {
  __shared__ int sstart[NUM_EXPERTS];
  __shared__ int stot[NUM_EXPERTS];
  const int tid = threadIdx.x;
  const int b = blockIdx.x;

  if (b == 256) {   // l_aux
    __shared__ float sme2[12][NUM_EXPERTS];
    __shared__ int sce2[12][NUM_EXPERTS];
    const float* me = reinterpret_cast<const float*>(ws + SC_ME);
    const uint16_t* ceh = reinterpret_cast<const uint16_t*>(ws + SC_CEH);
    const int e = tid & 15, grp = tid >> 4;   // 12 groups
    float ms = 0.f; int cs = 0;
    for (int k = grp; k < NBLK2; k += 12) {
      ms += me[k * NUM_EXPERTS + e];
      cs += ceh[e * NBLK2 + k];
    }
    sme2[grp][e] = ms; sce2[grp][e] = cs;
    __syncthreads();
    if (tid < NUM_EXPERTS) {
      float ssum = 0.f; int ce = 0;
#pragma unroll
      for (int g2 = 0; g2 < 12; g2++) { ssum += sme2[g2][tid]; ce += sce2[g2][tid]; }
      float prod = (ssum * (1.0f / N_TOKENS)) * ((float)ce * (1.0f / N_TOKENS));
      prod += __shfl_xor(prod, 1, 64);
      prod += __shfl_xor(prod, 2, 64);
      prod += __shfl_xor(prod, 4, 64);
      prod += __shfl_xor(prod, 8, 64);
      if (tid == 0) out[0] = prod * (float)NUM_EXPERTS;
    }
    return;
  }

  // ---- blocks 0..255 ----
  if (tid < 64) {   // per-block prefix: lane (e = tid>>2, q = tid&3)
    const int e = tid >> 2, q = tid & 3;
    const uint32_t* row =
        reinterpret_cast<const uint32_t*>(ws + SC_CNTH) + e * (NBLK2 / 2) + q * 64;
    const int limit = 2 * b;          // even -> u16 pairs never split
    int s_lt = 0, s_all = 0;
    for (int wd = 0; wd < 64; ++wd) {
      uint32_t v = row[wd];
      int pair = (int)(v & 0xFFFF) + (int)(v >> 16);
      s_all += pair;
      if (q * 128 + 2 * wd < limit) s_lt += pair;
    }
    s_lt += __shfl_xor(s_lt, 1, 64);  s_lt += __shfl_xor(s_lt, 2, 64);
    s_all += __shfl_xor(s_all, 1, 64); s_all += __shfl_xor(s_all, 2, 64);
    if (q == 0) { sstart[e] = s_lt; stot[e] = s_all; }
  }
  __syncthreads();

  if (tid < 64) {   // wave 0: ballot scatter (lane = token in chunk b)
    const int t = b * 64 + tid;
    const int v = ws[SC_E01 + t];
    const int e1 = v & 15, e2 = v >> 4;
    const unsigned long long below = (1ull << tid) - 1ull;
    int p1 = CAPACITY, p2 = CAPACITY;
    for (int e = 0; e < NUM_EXPERTS; e++) {
      unsigned long long m = __ballot(e1 == e) | __ballot(e2 == e);
      int r = __popcll(m & below);
      int sbase = sstart[e];
      if (e1 == e) p1 = sbase + r;
      if (e2 == e) p2 = sbase + r;
    }
    float tf = (float)t;   // exact in fp32
    if ((unsigned)p1 < (unsigned)CAPACITY) out[IDX_OFF + e1 * CAPACITY + p1] = tf;
    if ((unsigned)p2 < (unsigned)CAPACITY) out[IDX_OFF + e2 * CAPACITY + p2] = tf;
  } else {          // waves 1-2: fill -1 + expert_ids for 128 slots
    const int slot = b * 128 + (tid - 64);   // 0..32767
    const int e = slot >> 11;                // == b/16, uniform per block
    const int p = slot & (CAPACITY - 1);
    if (p >= stot[e]) out[IDX_OFF + slot] = -1.0f;
    out[EID_OFF + slot] = (float)e;
  }
}

extern "C" void kernel_launch(void* const* d_in, const int* in_sizes, int n_in,
                              void* d_out, int out_size, void* d_ws, size_t ws_size,
                              hipStream_t stream) {
  const float* x  = (const float*)d_in[0];
  const float* wg = (const float*)d_in[1];
  float* out = (float*)d_out;
  uint8_t* ws = (uint8_t*)d_ws;

  k_logits<<<GBLK, 512, 0, stream>>>(x, wg, out, ws);
  k_tail<<<257, 192, 0, stream>>>(ws, out);
}